// Round 7
// baseline (636.146 us; speedup 1.0000x reference)
//
#include <hip/hip_runtime.h>

// BiLSTM fused: B=512, T=200, E=H=128, 2 layers, bidir, residual on layer 1,
// out = 0.5*(fw+bw).  Per scan step z = W*x(t) + U*h(t-1) + b all in MFMA;
// h exchanged via LDS with raw s_barrier + lgkmcnt(0) (vmcnt never drained).
// Round 6 (fixed): LUT dropped (it serialized the per-CU LDS pipe: +8e6
// bank-conflict cycles); gates via v_exp_f32/v_rcp_f32 on the trans pipe.
// VALU diet: bias folded into MFMA C-operand, pointer-bump addressing,
// cvt_pkrtz packing, packed-f16 residual math.  W-MFMAs issue before U-MFMAs
// so the h ds_read latency hides under independent MFMA issue.

typedef _Float16 f16;
typedef _Float16 f16x2 __attribute__((ext_vector_type(2)));
typedef _Float16 f16x4 __attribute__((ext_vector_type(4)));
typedef _Float16 f16x8 __attribute__((ext_vector_type(8)));
typedef float    f32x4 __attribute__((ext_vector_type(4)));

#define B_   512
#define T_   200
#define E_   128
#define H_   128
#define G4_  512
#define M_   (B_*T_)   // 102400

static __device__ __forceinline__ float rcpa(float x) {
#if __has_builtin(__builtin_amdgcn_rcpf)
  return __builtin_amdgcn_rcpf(x);
#else
  return 1.f / x;
#endif
}
static __device__ __forceinline__ float exp2a(float x) {
#if __has_builtin(__builtin_amdgcn_exp2f)
  return __builtin_amdgcn_exp2f(x);
#else
  return exp2f(x);
#endif
}
static __device__ __forceinline__ f16x2 pk2(float lo, float hi) {
  return __builtin_bit_cast(f16x2, __builtin_amdgcn_cvt_pkrtz(lo, hi));
}

static __device__ __forceinline__ void lgkm_barrier() {
  asm volatile("s_waitcnt lgkmcnt(0)" ::: "memory");
  __builtin_amdgcn_s_barrier();
}

// ---------- prep: x fp32 -> f16 ----------
__global__ __launch_bounds__(256)
void cvt_x(const float* __restrict__ x, f16* __restrict__ xh) {
  const int n8 = M_ * E_ / 8;
  for (int i = blockIdx.x * 256 + threadIdx.x; i < n8; i += gridDim.x * 256) {
    const float4 a = ((const float4*)x)[i * 2];
    const float4 b = ((const float4*)x)[i * 2 + 1];
    f16x8 v;
    v[0] = (f16)a.x; v[1] = (f16)a.y; v[2] = (f16)a.z; v[3] = (f16)a.w;
    v[4] = (f16)b.x; v[5] = (f16)b.y; v[6] = (f16)b.z; v[7] = (f16)b.w;
    *(f16x8*)(xh + (size_t)i * 8) = v;
  }
}

// ---------- prep: W,U [slab][128][512] fp32 -> [slab][512][128] f16 ----------
// 8 slabs: 4 of W then 4 of U.  g-gate rows (cols 256..383) prescaled x2 so
// tanh(zg) = 2*sigma(zg') - 1.
__global__ __launch_bounds__(256)
void prep_w(const float* __restrict__ W, const float* __restrict__ U,
            f16* __restrict__ Wt, f16* __restrict__ Ut) {
  const int m = blockIdx.x;                     // 0..7
  const float* s = (m < 4 ? W + (size_t)m * E_ * G4_ : U + (size_t)(m - 4) * E_ * G4_);
  f16* d        = (m < 4 ? Wt + (size_t)m * E_ * G4_ : Ut + (size_t)(m - 4) * E_ * G4_);
  for (int i = threadIdx.x; i < E_ * G4_; i += 256) {
    const int k = i >> 9, g = i & 511;
    float v = s[i];
    if ((g >> 7) == 2) v *= 2.f;
    d[(size_t)g * E_ + k] = (f16)v;
  }
}

// ---------- fused recurrent scan ----------
// grid 64: dir = bx>>5, rows [R0, R0+16).  block 512 = 8 waves.
// Wave wv owns gate-cols {g*128 + wv*16 + c}.  Lane l: batch row l&15,
// kg = l>>4, output cells kg*4+i of hidden slice [wv*16, wv*16+16).
template <int LAYER>
__global__ __launch_bounds__(512, 2)
void scan_fused(const f16* __restrict__ in,    // L0: xh [M][128]; L1: h0 [2][M][128]
                const f16* __restrict__ Utl,   // [2][512][128] this layer (transposed, g x2)
                const f16* __restrict__ Wtl,   // [2][512][128] this layer (transposed, g x2)
                const float* __restrict__ bl,  // [2][512] this layer (raw)
                const f16* __restrict__ res,   // L1: h0 [2][M][128]
                f16* __restrict__ hout)        // [2][M][128]
{
  __shared__ f16 hsh[2][16][136];

  const int tid  = threadIdx.x;
  const int lane = tid & 63;
  const int wv   = tid >> 6;
  const int row  = lane & 15;
  const int kg   = lane >> 4;
  const int bx   = blockIdx.x;
  const int dir  = bx >> 5;
  const int R0   = (bx & 31) * 16;
  const int coff = wv * 16 + kg * 4;

  const f16* Ud = Utl + (size_t)dir * G4_ * E_;
  const f16* Wd = Wtl + (size_t)dir * G4_ * E_;
  const float* bd = bl + (size_t)dir * G4_;
  const f16* ind  = in + (LAYER == 1 ? (size_t)dir * M_ * H_ : 0);
  f16* houtd      = hout + (size_t)dir * M_ * H_;

  // stationary A-frags (vector loads from pre-transposed f16)
  f16x8 aU[4][4], aW[4][4];
#pragma unroll
  for (int g = 0; g < 4; ++g) {
    const size_t gcol = (size_t)(g * 128 + wv * 16 + row) * E_;
#pragma unroll
    for (int kk = 0; kk < 4; ++kk) {
      aU[g][kk] = *(const f16x8*)(Ud + gcol + kk * 32 + kg * 8);
      aW[g][kk] = *(const f16x8*)(Wd + gcol + kk * 32 + kg * 8);
    }
  }
  // bias (g-gate x2 to match prescaled weights); used as MFMA C-init each step
  f32x4 zb[4];
#pragma unroll
  for (int g = 0; g < 4; ++g) {
#pragma unroll
    for (int i = 0; i < 4; ++i) {
      const float v = bd[g * 128 + coff + i];
      zb[g][i] = (g == 2) ? 2.f * v : v;
    }
  }

  // zero h(-1)
  for (int i = tid; i < 2 * 16 * 136; i += 512) ((f16*)hsh)[i] = (f16)0.f;

  const int t0 = dir ? (T_ - 1) : 0;
  const int ts = dir ? -1 : 1;

  const f16* inrow  = ind + (size_t)(R0 + row) * T_ * E_ + kg * 8;
  const f16* resrow = (LAYER == 1)
      ? res + (size_t)dir * M_ * H_ + (size_t)(R0 + row) * T_ * H_ + coff : nullptr;
  f16* outptr = houtd + (size_t)(R0 + row) * T_ * H_ + (size_t)t0 * H_ + coff;

  float cc0 = 0.f, cc1 = 0.f, cc2 = 0.f, cc3 = 0.f;

  // register pipelines: xpA consumed at even s (holds x(t+1)), xpB at odd.
  const f16* xptrA = inrow + (long)(t0 + ts) * E_;
  const f16* xptrB = inrow + (long)(t0 + 2 * ts) * E_;
  f16x8 xpA[4], xpB[4], xP[4];
#pragma unroll
  for (int kk = 0; kk < 4; ++kk) {
    xP[kk]  = *(const f16x8*)(inrow + (long)t0 * E_ + kk * 32);
    xpA[kk] = *(const f16x8*)(xptrA + kk * 32);
    xpB[kk] = *(const f16x8*)(xptrB + kk * 32);
  }
  const f16* rptrA = nullptr; const f16* rptrB = nullptr;
  uint2 rvA = {}, rvB = {};
  if (LAYER == 1) {
    rptrA = resrow + (long)t0 * H_;
    rptrB = resrow + (long)(t0 + ts) * H_;
    rvA = *(const uint2*)rptrA;
    rvB = *(const uint2*)rptrB;
  }

  lgkm_barrier();   // hsh zero visible

  // prologue: zA = b + W*x(t0)
  f32x4 zA[4], zB[4];
#pragma unroll
  for (int g = 0; g < 4; ++g) {
    zA[g] = __builtin_amdgcn_mfma_f32_16x16x32_f16(aW[g][0], xP[0], zb[g], 0, 0, 0);
#pragma unroll
    for (int kk = 1; kk < 4; ++kk)
      zA[g] = __builtin_amdgcn_mfma_f32_16x16x32_f16(aW[g][kk], xP[kk], zA[g], 0, 0, 0);
  }

  constexpr float NL2E  = -1.4426950408889634f;   // -log2(e)
  constexpr float NL2E2 = -2.8853900817779268f;   // -2*log2(e)

  auto step = [&](f32x4 (&zc)[4], f32x4 (&zn)[4], f16x8 (&xp)[4],
                  const f16*& xptr, uint2& rv, const f16*& rptr,
                  int rp, int wp) {
    // (1) h(t-1) ds_reads issue first; latency covered by (2)
    f16x8 hf[4];
#pragma unroll
    for (int kk = 0; kk < 4; ++kk) hf[kk] = *(const f16x8*)&hsh[rp][row][kk * 32 + kg * 8];

    // (2) zn = b + W*x(t+1)  (independent of h)
#pragma unroll
    for (int g = 0; g < 4; ++g)
      zn[g] = __builtin_amdgcn_mfma_f32_16x16x32_f16(aW[g][0], xp[0], zb[g], 0, 0, 0);
#pragma unroll
    for (int kk = 1; kk < 4; ++kk) {
      zn[0] = __builtin_amdgcn_mfma_f32_16x16x32_f16(aW[0][kk], xp[kk], zn[0], 0, 0, 0);
      zn[1] = __builtin_amdgcn_mfma_f32_16x16x32_f16(aW[1][kk], xp[kk], zn[1], 0, 0, 0);
      zn[2] = __builtin_amdgcn_mfma_f32_16x16x32_f16(aW[2][kk], xp[kk], zn[2], 0, 0, 0);
      zn[3] = __builtin_amdgcn_mfma_f32_16x16x32_f16(aW[3][kk], xp[kk], zn[3], 0, 0, 0);
    }

    // (3) refill xp <- x(t+3) (pointer bump; const offsets fold into loads)
    xptr += 2 * ts * E_;
#pragma unroll
    for (int kk = 0; kk < 4; ++kk) xp[kk] = *(const f16x8*)(xptr + kk * 32);
    f16x2 rva, rvb;
    if (LAYER == 1) {
      rva = __builtin_bit_cast(f16x2, rv.x);
      rvb = __builtin_bit_cast(f16x2, rv.y);
      rptr += 2 * ts * H_;
      rv = *(const uint2*)rptr;
    }

    // (4) zc += U*h(t-1)
#pragma unroll
    for (int kk = 0; kk < 4; ++kk) {
      zc[0] = __builtin_amdgcn_mfma_f32_16x16x32_f16(aU[0][kk], hf[kk], zc[0], 0, 0, 0);
      zc[1] = __builtin_amdgcn_mfma_f32_16x16x32_f16(aU[1][kk], hf[kk], zc[1], 0, 0, 0);
      zc[2] = __builtin_amdgcn_mfma_f32_16x16x32_f16(aU[2][kk], hf[kk], zc[2], 0, 0, 0);
      zc[3] = __builtin_amdgcn_mfma_f32_16x16x32_f16(aU[3][kk], hf[kk], zc[3], 0, 0, 0);
    }

    // (5) gates: sigma = rcp(1+exp2(-x*log2e)); tanh(g) via prescaled x2
    float hv[4];
    float cc[4] = {cc0, cc1, cc2, cc3};
#pragma unroll
    for (int i = 0; i < 4; ++i) {
      const float ei = exp2a(zc[0][i] * NL2E);
      const float ef = exp2a(zc[1][i] * NL2E);
      const float eg = exp2a(zc[2][i] * NL2E);   // zg already doubled
      const float eo = exp2a(zc[3][i] * NL2E);
      const float ig = rcpa(1.f + ei);
      const float fg = rcpa(1.f + ef);
      const float gg = fmaf(2.f, rcpa(1.f + eg), -1.f);
      const float og = rcpa(1.f + eo);
      cc[i] = fmaf(fg, cc[i], ig * gg);
      const float ec = exp2a(cc[i] * NL2E2);
      const float tc = fmaf(2.f, rcpa(1.f + ec), -1.f);
      hv[i] = og * tc;
    }
    cc0 = cc[0]; cc1 = cc[1]; cc2 = cc[2]; cc3 = cc[3];

    // (6) pack + stores
    const f16x2 h01 = pk2(hv[0], hv[1]);
    const f16x2 h23 = pk2(hv[2], hv[3]);
    uint2 hp;
    hp.x = __builtin_bit_cast(unsigned int, h01);
    hp.y = __builtin_bit_cast(unsigned int, h23);
    *(uint2*)&hsh[wp][row][coff] = hp;

    if (LAYER == 0) {
      *(uint2*)outptr = hp;
    } else {
      const f16x2 half2 = {(f16)0.5f, (f16)0.5f};
      const f16x2 o01 = (h01 + rva) * half2;
      const f16x2 o23 = (h23 + rvb) * half2;
      uint2 o;
      o.x = __builtin_bit_cast(unsigned int, o01);
      o.y = __builtin_bit_cast(unsigned int, o23);
      *(uint2*)outptr = o;
    }
    outptr += ts * H_;

    lgkm_barrier();   // h(t) visible; vmcnt NOT drained
  };

  for (int k = 0; k < T_ / 2; ++k) {
    step(zA, zB, xpA, xptrA, rvA, rptrA, 0, 1);
    step(zB, zA, xpB, xptrB, rvB, rptrB, 1, 0);
  }
}

__global__ __launch_bounds__(256)
void final_add(const f16* __restrict__ a, const f16* __restrict__ b,
               float* __restrict__ o)
{
  const int n8 = M_ * H_ / 8;
  for (int i = blockIdx.x * 256 + threadIdx.x; i < n8; i += gridDim.x * 256) {
    const f16x8 va = *(const f16x8*)(a + (size_t)i * 8);
    const f16x8 vb = *(const f16x8*)(b + (size_t)i * 8);
    float4 o0, o1;
    o0.x = (float)va[0] + (float)vb[0];  o0.y = (float)va[1] + (float)vb[1];
    o0.z = (float)va[2] + (float)vb[2];  o0.w = (float)va[3] + (float)vb[3];
    o1.x = (float)va[4] + (float)vb[4];  o1.y = (float)va[5] + (float)vb[5];
    o1.z = (float)va[6] + (float)vb[6];  o1.w = (float)va[7] + (float)vb[7];
    *(float4*)(o + (size_t)i * 8)     = o0;
    *(float4*)(o + (size_t)i * 8 + 4) = o1;
  }
}

extern "C" void kernel_launch(void* const* d_in, const int* in_sizes, int n_in,
                              void* d_out, int out_size, void* d_ws, size_t ws_size,
                              hipStream_t stream) {
  const float* x = (const float*)d_in[0];
  const float* W = (const float*)d_in[1];  // [2][2][128][512]
  const float* U = (const float*)d_in[2];  // [2][2][128][512]
  const float* b = (const float*)d_in[3];  // [2][2][512]
  float* out = (float*)d_out;

  char* ws = (char*)d_ws;
  // 2KB guards around xh: register pipelines prefetch up to 2 timesteps
  // (512B) past either end of a row.
  f16* xh = (f16*)(ws + 2048);                     // [M][128]    26.2 MB
  f16* h0 = xh + (size_t)M_ * E_ + 1024;           // [2][M][128] 52.4 MB (+2KB guard)
  f16* h1 = h0 + (size_t)2 * M_ * H_ + 1024;       // [2][M][128] 52.4 MB (+2KB guard)
  f16* Wt = h1 + (size_t)2 * M_ * H_ + 1024;       // [2][2][512][128] 1 MB
  f16* Ut = Wt + (size_t)4 * G4_ * E_;             // [2][2][512][128] 1 MB

  const size_t WTL = (size_t)2 * G4_ * E_;         // f16 per layer of Wt/Ut
  const size_t BL  = 2 * G4_;

  cvt_x<<<dim3(2048), 256, 0, stream>>>(x, xh);
  prep_w<<<dim3(8), 256, 0, stream>>>(W, U, Wt, Ut);
  scan_fused<0><<<dim3(64), 512, 0, stream>>>(xh, Ut, Wt, b, nullptr, h0);
  scan_fused<1><<<dim3(64), 512, 0, stream>>>(h0, Ut + WTL, Wt + WTL, b + BL, h0, h1);
  final_add<<<dim3(2048), 256, 0, stream>>>(h1, h1 + (size_t)M_ * H_, out);
}